// Round 2
// baseline (2193.145 us; speedup 1.0000x reference)
//
#include <hip/hip_runtime.h>

typedef unsigned int u32;
typedef unsigned short u16;

#define NN 100000
#define EE 1600000
#define SS 10000
#define GG 256
#define NSCAN ((NN + 1023) / 1024)

// param block offsets (f32 elements)
#define O_W1   0
#define O_B1   65536
#define O_G1   66048
#define O_BE1  66560
#define O_W2   67072
#define O_B2   132608
#define O_G2   133120
#define O_BE2  133632
#define O_EPS  134144
#define O_L1W  134148
#define O_L1B  199684
#define O_L2W  199812
#define O_L2B  201092
#define NPAR   201102

typedef __bf16 bf16x8_t __attribute__((ext_vector_type(8)));
typedef float f32x4_t __attribute__((ext_vector_type(4)));
typedef u32 u32x4_t __attribute__((ext_vector_type(4)));

__device__ __forceinline__ float bf2f(u16 u) {
  union { u32 i; float f; } x; x.i = ((u32)u) << 16; return x.f;
}
__device__ __forceinline__ u16 f2bf(float f) {
  union { float f; u32 i; } x; x.f = f;
  u32 r = x.i + 0x7fffu + ((x.i >> 16) & 1u);
  return (u16)(r >> 16);
}
__device__ __forceinline__ int lbound(const int* __restrict__ a, int n, int key) {
  int lo = 0, hi = n;
  while (lo < hi) { int mid = (lo + hi) >> 1; if (a[mid] < key) lo = mid + 1; else hi = mid; }
  return lo;
}

// ---------------- dtype sniff: 1 = inputs are f32, 0 = bf16 ----------------
__global__ void k_sniff(const u16* __restrict__ x, int* __restrict__ flag) {
  __shared__ int cnt;
  if (threadIdx.x == 0) cnt = 0;
  __syncthreads();
  int weird = 0;
  for (int i = threadIdx.x; i < 8192; i += 256) {
    u16 v = x[i];
    int e = (v >> 7) & 0xff;            // bf16 exponent field
    if (e >= 0xC0) weird++;             // |val| >= 2^65 or inf/nan: impossible for N(0,1) bf16
  }
  atomicAdd(&cnt, weird);
  __syncthreads();
  if (threadIdx.x == 0) *flag = (cnt > 64) ? 1 : 0;
}

// ---------------- convert all params into f32 block P ----------------
__global__ __launch_bounds__(256) void k_cvt_params(
    const void* pW1, const void* pb1, const void* pg1, const void* pbe1,
    const void* pW2, const void* pb2, const void* pg2, const void* pbe2,
    const void* peps, const void* pl1w, const void* pl1b, const void* pl2w, const void* pl2b,
    const int* __restrict__ flagp, float* __restrict__ P) {
  int i = blockIdx.x * 256 + threadIdx.x;
  if (i >= NPAR) return;
  const void* src; int rel;
  if      (i < O_B1)  { src = pW1;  rel = i - O_W1; }
  else if (i < O_G1)  { src = pb1;  rel = i - O_B1; }
  else if (i < O_BE1) { src = pg1;  rel = i - O_G1; }
  else if (i < O_W2)  { src = pbe1; rel = i - O_BE1; }
  else if (i < O_B2)  { src = pW2;  rel = i - O_W2; }
  else if (i < O_G2)  { src = pb2;  rel = i - O_B2; }
  else if (i < O_BE2) { src = pg2;  rel = i - O_G2; }
  else if (i < O_EPS) { src = pbe2; rel = i - O_BE2; }
  else if (i < O_L1W) { src = peps; rel = i - O_EPS; }
  else if (i < O_L1B) { src = pl1w; rel = i - O_L1W; }
  else if (i < O_L2W) { src = pl1b; rel = i - O_L1B; }
  else if (i < O_L2B) { src = pl2w; rel = i - O_L2W; }
  else                { src = pl2b; rel = i - O_L2B; }
  float v = (*flagp) ? ((const float*)src)[rel] : bf2f(((const u16*)src)[rel]);
  P[i] = v;
}

// ---------------- split W1/W2 into hi/lo bf16 ----------------
__global__ __launch_bounds__(256) void k_splitW(const float* __restrict__ P,
                                                u16* __restrict__ W1hi, u16* __restrict__ W1lo,
                                                u16* __restrict__ W2hi, u16* __restrict__ W2lo) {
  int i = blockIdx.x * 256 + threadIdx.x;
  if (i >= 131072) return;
  float w; u16 *hi, *lo; int rel;
  if (i < 65536) { rel = i; w = P[O_W1 + rel]; hi = W1hi; lo = W1lo; }
  else           { rel = i - 65536; w = P[O_W2 + rel]; hi = W2hi; lo = W2lo; }
  u16 h = f2bf(w);
  float r = w - bf2f(h);
  hi[rel] = h; lo[rel] = f2bf(r);
}

// ---------------- CSR build ----------------
__global__ __launch_bounds__(256) void k_hist(const int* __restrict__ dst, int* __restrict__ cnt) {
  int i = blockIdx.x * 256 + threadIdx.x;
  if (i < EE) atomicAdd(&cnt[dst[i]], 1);
}

__global__ __launch_bounds__(256) void k_scan1(const int* __restrict__ cnt, int* __restrict__ bsum) {
  __shared__ int sh[256];
  int base = blockIdx.x * 1024 + threadIdx.x * 4;
  int s = 0;
#pragma unroll
  for (int i = 0; i < 4; i++) { int idx = base + i; s += (idx < NN) ? cnt[idx] : 0; }
  sh[threadIdx.x] = s; __syncthreads();
  for (int o = 128; o > 0; o >>= 1) {
    if (threadIdx.x < o) sh[threadIdx.x] += sh[threadIdx.x + o];
    __syncthreads();
  }
  if (threadIdx.x == 0) bsum[blockIdx.x] = sh[0];
}

__global__ void k_scan2(int* __restrict__ bsum, int* __restrict__ off) {
  if (threadIdx.x == 0 && blockIdx.x == 0) {
    int run = 0;
    for (int i = 0; i < NSCAN; i++) { int v = bsum[i]; bsum[i] = run; run += v; }
    off[NN] = run;
  }
}

__global__ __launch_bounds__(256) void k_scan3(const int* __restrict__ cnt, const int* __restrict__ bsum,
                                               int* __restrict__ off) {
  __shared__ int sh[256];
  int base = blockIdx.x * 1024 + threadIdx.x * 4;
  int v[4]; int s = 0;
#pragma unroll
  for (int i = 0; i < 4; i++) { int idx = base + i; v[i] = (idx < NN) ? cnt[idx] : 0; s += v[i]; }
  sh[threadIdx.x] = s; __syncthreads();
  for (int o = 1; o < 256; o <<= 1) {
    int add = (threadIdx.x >= o) ? sh[threadIdx.x - o] : 0;
    __syncthreads();
    sh[threadIdx.x] += add;
    __syncthreads();
  }
  int run = sh[threadIdx.x] - s + bsum[blockIdx.x];
#pragma unroll
  for (int i = 0; i < 4; i++) { int idx = base + i; if (idx < NN) { off[idx] = run; run += v[i]; } }
}

__global__ __launch_bounds__(256) void k_fill(const int* __restrict__ src, const int* __restrict__ dst,
                                              const int* __restrict__ off, int* __restrict__ cur,
                                              int* __restrict__ csr) {
  int i = blockIdx.x * 256 + threadIdx.x;
  if (i >= EE) return;
  int d = dst[i];
  int p = off[d] + atomicAdd(&cur[d], 1);
  csr[p] = src[i];
}

// ---------------- layer-0 aggregation (dual-dtype input) ----------------
__global__ __launch_bounds__(256) void k_agg0(const void* __restrict__ xraw, const int* __restrict__ off,
                                              const int* __restrict__ csr, const float* __restrict__ P,
                                              const int* __restrict__ flagp, float* __restrict__ t) {
  int w = (blockIdx.x * 256 + threadIdx.x) >> 6;
  int lane = threadIdx.x & 63;
  if (w >= NN) return;
  float ev = 1.0f + P[O_EPS + 0];
  float a0, a1;
  int i = off[w], e = off[w + 1];
  if (*flagp) {
    const float2* xr = (const float2*)xraw;
    float2 d = xr[w * 64 + lane];
    a0 = ev * d.x; a1 = ev * d.y;
    for (; i < e; i++) { float2 dd = xr[csr[i] * 64 + lane]; a0 += dd.x; a1 += dd.y; }
  } else {
    const u32* xr = (const u32*)xraw;
    u32 d = xr[w * 64 + lane];
    a0 = ev * bf2f((u16)(d & 0xffffu)); a1 = ev * bf2f((u16)(d >> 16));
    for (; i < e; i++) {
      u32 dd = xr[csr[i] * 64 + lane];
      a0 += bf2f((u16)(dd & 0xffffu)); a1 += bf2f((u16)(dd >> 16));
    }
  }
  float2 o; o.x = a0; o.y = a1;
  ((float2*)t)[w * 64 + lane] = o;
}

// ---------------- aggregation, f32 input (layers 1..3) ----------------
__global__ __launch_bounds__(256) void k_aggf(const float* __restrict__ x, const int* __restrict__ off,
                                              const int* __restrict__ csr, const float* __restrict__ P,
                                              int layer, float* __restrict__ t) {
  int w = (blockIdx.x * 256 + threadIdx.x) >> 6;
  int lane = threadIdx.x & 63;
  if (w >= NN) return;
  const float2* xr = (const float2*)x;
  float ev = 1.0f + P[O_EPS + layer];
  float2 d = xr[w * 64 + lane];
  float a0 = ev * d.x, a1 = ev * d.y;
  int i = off[w], e = off[w + 1];
  for (; i + 1 < e; i += 2) {
    float2 d0 = xr[csr[i] * 64 + lane];
    float2 d1 = xr[csr[i + 1] * 64 + lane];
    a0 += d0.x + d1.x; a1 += d0.y + d1.y;
  }
  if (i < e) { float2 d0 = xr[csr[i] * 64 + lane]; a0 += d0.x; a1 += d0.y; }
  float2 o; o.x = a0; o.y = a1;
  ((float2*)t)[w * 64 + lane] = o;
}

// ---------------- GEMM: out[n,o] = sum_k A[n,k]*W[o,k]; A f32, W split bf16 ----------------
__global__ __launch_bounds__(256) void k_gemm_split(const float* __restrict__ A, const u16* __restrict__ Whi,
                                                    const u16* __restrict__ Wlo, const float* __restrict__ bias,
                                                    float* __restrict__ out) {
  int wave = threadIdx.x >> 6;
  int lane = threadIdx.x & 63;
  int r0 = blockIdx.x * 64 + wave * 16;
  int nidx = lane & 15;
  int q = lane >> 4;
  int arow = r0 + nidx;
  f32x4_t acc[8];
  f32x4_t z = {0.f, 0.f, 0.f, 0.f};
#pragma unroll
  for (int ot = 0; ot < 8; ot++) acc[ot] = z;
#pragma unroll
  for (int ks = 0; ks < 4; ks++) {
    float av[8];
    if (arow < NN) {
      f32x4_t lo4 = *(const f32x4_t*)(A + arow * 128 + ks * 32 + q * 8);
      f32x4_t hi4 = *(const f32x4_t*)(A + arow * 128 + ks * 32 + q * 8 + 4);
#pragma unroll
      for (int j = 0; j < 4; j++) { av[j] = lo4[j]; av[4 + j] = hi4[j]; }
    } else {
#pragma unroll
      for (int j = 0; j < 8; j++) av[j] = 0.f;
    }
    u32x4_t ahp, alp;
#pragma unroll
    for (int j = 0; j < 4; j++) {
      u16 h0 = f2bf(av[2 * j]), h1 = f2bf(av[2 * j + 1]);
      float r0f = av[2 * j] - bf2f(h0), r1f = av[2 * j + 1] - bf2f(h1);
      ahp[j] = (u32)h0 | ((u32)h1 << 16);
      alp[j] = (u32)f2bf(r0f) | ((u32)f2bf(r1f) << 16);
    }
    bf16x8_t ah = __builtin_bit_cast(bf16x8_t, ahp);
    bf16x8_t al = __builtin_bit_cast(bf16x8_t, alp);
#pragma unroll
    for (int ot = 0; ot < 8; ot++) {
      int woff = (ot * 16 + nidx) * 128 + ks * 32 + q * 8;
      bf16x8_t wh = __builtin_bit_cast(bf16x8_t, *(const u32x4_t*)(Whi + woff));
      bf16x8_t wl = __builtin_bit_cast(bf16x8_t, *(const u32x4_t*)(Wlo + woff));
      acc[ot] = __builtin_amdgcn_mfma_f32_16x16x32_bf16(ah, wh, acc[ot], 0, 0, 0);
      acc[ot] = __builtin_amdgcn_mfma_f32_16x16x32_bf16(al, wh, acc[ot], 0, 0, 0);
      acc[ot] = __builtin_amdgcn_mfma_f32_16x16x32_bf16(ah, wl, acc[ot], 0, 0, 0);
    }
  }
#pragma unroll
  for (int ot = 0; ot < 8; ot++) {
    float bv = bias[ot * 16 + nidx];
#pragma unroll
    for (int j = 0; j < 4; j++) {
      int row = r0 + q * 4 + j;
      if (row < NN) out[row * 128 + ot * 16 + nidx] = acc[ot][j] + bv;
    }
  }
}

// ---------------- column stats (sum, sumsq) ----------------
__global__ __launch_bounds__(256) void k_stats(const float* __restrict__ p, float* __restrict__ st) {
  int t = threadIdx.x;
  int col = t & 127, rl = t >> 7;
  int rbeg = blockIdx.x * 512;
  int rend = min(NN, rbeg + 512);
  float s = 0.f, sq = 0.f;
  for (int r = rbeg + rl; r < rend; r += 2) {
    float v = p[r * 128 + col];
    s += v; sq += v * v;
  }
  atomicAdd(&st[col], s);
  atomicAdd(&st[128 + col], sq);
}

// ---------------- BN + ReLU apply (f32) ----------------
__global__ __launch_bounds__(256) void k_bnapply(const float* __restrict__ p, const float* __restrict__ st,
                                                 const float* __restrict__ gw, const float* __restrict__ bw,
                                                 float* __restrict__ outb) {
  __shared__ float sc[256];
  int t = threadIdx.x;
  if (t < 128) {
    float mu = st[t] * (1.0f / NN);
    float var = st[128 + t] * (1.0f / NN) - mu * mu;
    var = fmaxf(var, 0.f);
    float r = rsqrtf(var + 1e-5f);
    float scl = gw[t] * r;
    sc[t] = scl;
    sc[128 + t] = bw[t] - mu * scl;
  }
  __syncthreads();
  int i = blockIdx.x * 256 + t;
  if (i >= NN * 32) return;  // float4 chunks
  float4 d = ((const float4*)p)[i];
  int c0 = (i * 4) & 127;
  d.x = fmaxf(d.x * sc[c0] + sc[128 + c0], 0.f);
  d.y = fmaxf(d.y * sc[c0 + 1] + sc[128 + c0 + 1], 0.f);
  d.z = fmaxf(d.z * sc[c0 + 2] + sc[128 + c0 + 2], 0.f);
  d.w = fmaxf(d.w * sc[c0 + 3] + sc[128 + c0 + 3], 0.f);
  ((float4*)outb)[i] = d;
}

// ---------------- per-layer subgraph mean (sorted segments) ----------------
__global__ __launch_bounds__(256) void k_subpool(const float* __restrict__ y, const int* __restrict__ n2s,
                                                 float* __restrict__ sub, int layer) {
  int s = (blockIdx.x * 256 + threadIdx.x) >> 6;
  int lane = threadIdx.x & 63;
  if (s >= SS) return;
  int r0 = lbound(n2s, NN, s), r1 = lbound(n2s, NN, s + 1);
  const float2* yr = (const float2*)y;
  float a0 = 0.f, a1 = 0.f;
  for (int r = r0; r < r1; r++) {
    float2 d = yr[r * 64 + lane];
    a0 += d.x; a1 += d.y;
  }
  int c = r1 - r0;
  float inv = 1.0f / (float)(c > 0 ? c : 1);
  float2 v; v.x = a0 * inv; v.y = a1 * inv;
  *(float2*)(sub + (size_t)s * 512 + layer * 128 + lane * 2) = v;
}

// ---------------- graph mean over subgraphs (sorted segments) ----------------
__global__ __launch_bounds__(256) void k_graphpool(const float* __restrict__ sub, const int* __restrict__ s2g,
                                                   float* __restrict__ gph) {
  int g = (blockIdx.x * 256 + threadIdx.x) >> 6;
  int lane = threadIdx.x & 63;
  if (g >= GG) return;
  int r0 = lbound(s2g, SS, g), r1 = lbound(s2g, SS, g + 1);
  float a[8] = {0.f, 0.f, 0.f, 0.f, 0.f, 0.f, 0.f, 0.f};
  for (int s = r0; s < r1; s++) {
    const float* row = sub + (size_t)s * 512 + lane * 8;
#pragma unroll
    for (int j = 0; j < 8; j++) a[j] += row[j];
  }
  int c = r1 - r0;
  float inv = 1.0f / (float)(c > 0 ? c : 1);
  float* orow = gph + (size_t)g * 512 + lane * 8;
#pragma unroll
  for (int j = 0; j < 8; j++) orow[j] = a[j] * inv;
}

// ---------------- head: lin1+relu, lin2, log_softmax ----------------
__global__ __launch_bounds__(128) void k_head(const float* __restrict__ gph, const float* __restrict__ P,
                                              const int* __restrict__ flagp, void* __restrict__ out) {
  __shared__ float gsh[512];
  __shared__ float hsh[128];
  __shared__ float lsh[12];
  int g = blockIdx.x, t = threadIdx.x;
  for (int i = t; i < 512; i += 128) gsh[i] = gph[(size_t)g * 512 + i];
  __syncthreads();
  float acc = P[O_L1B + t];
  const float4* wr = (const float4*)(P + O_L1W + t * 512);
  for (int kb = 0; kb < 128; kb++) {
    float4 w = wr[kb];
    int k = kb * 4;
    acc += gsh[k] * w.x + gsh[k + 1] * w.y + gsh[k + 2] * w.z + gsh[k + 3] * w.w;
  }
  hsh[t] = fmaxf(acc, 0.f);
  __syncthreads();
  if (t < 10) {
    float a = P[O_L2B + t];
    const float* w2r = P + O_L2W + t * 128;
    for (int k = 0; k < 128; k++) a += hsh[k] * w2r[k];
    lsh[t] = a;
  }
  __syncthreads();
  if (t == 0) {
    float m = -1e30f;
    for (int c = 0; c < 10; c++) m = fmaxf(m, lsh[c]);
    float se = 0.f;
    for (int c = 0; c < 10; c++) se += expf(lsh[c] - m);
    lsh[10] = m + logf(se);
  }
  __syncthreads();
  if (t < 10) {
    float v = lsh[t] - lsh[10];
    if (*flagp) ((float*)out)[g * 10 + t] = v;
    else        ((u16*)out)[g * 10 + t] = f2bf(v);
  }
}

extern "C" void kernel_launch(void* const* d_in, const int* in_sizes, int n_in,
                              void* d_out, int out_size, void* d_ws, size_t ws_size,
                              hipStream_t stream) {
  const void* x   = d_in[0];
  const int* ei   = (const int*)d_in[1];
  const int* n2s  = (const int*)d_in[2];
  const int* s2g  = (const int*)d_in[3];

  char* ws = (char*)d_ws;
  size_t o = 0;
  auto alloc = [&](size_t b) -> void* {
    void* p = ws + o;
    o += (b + 255) & ~(size_t)255;
    return p;
  };
  int* flag   = (int*)alloc(256);
  int* off    = (int*)alloc((NN + 1) * 4);
  int* cnt    = (int*)alloc(NN * 4);
  int* bsum   = (int*)alloc(NSCAN * 4);
  int* csr    = (int*)alloc((size_t)EE * 4);
  float* X    = (float*)alloc((size_t)NN * 128 * 4);
  float* T    = (float*)alloc((size_t)NN * 128 * 4);
  float* Pb   = (float*)alloc((size_t)NN * 128 * 4);
  float* sub  = (float*)alloc((size_t)SS * 512 * 4);
  float* gph  = (float*)alloc((size_t)GG * 512 * 4);
  float* stats = (float*)alloc(8 * 256 * 4);
  float* P    = (float*)alloc((size_t)NPAR * 4);
  u16* W1hi   = (u16*)alloc(65536 * 2);
  u16* W1lo   = (u16*)alloc(65536 * 2);
  u16* W2hi   = (u16*)alloc(65536 * 2);
  u16* W2lo   = (u16*)alloc(65536 * 2);

  const int* esrc = ei;
  const int* edst = ei + EE;

  hipMemsetAsync(cnt, 0, NN * 4, stream);
  hipMemsetAsync(stats, 0, 8 * 256 * 4, stream);

  k_sniff<<<dim3(1), dim3(256), 0, stream>>>((const u16*)x, flag);
  k_cvt_params<<<dim3((NPAR + 255) / 256), dim3(256), 0, stream>>>(
      d_in[4], d_in[5], d_in[6], d_in[7], d_in[8], d_in[9], d_in[10], d_in[11],
      d_in[12], d_in[13], d_in[14], d_in[15], d_in[16], flag, P);
  k_splitW<<<dim3(512), dim3(256), 0, stream>>>(P, W1hi, W1lo, W2hi, W2lo);

  k_hist<<<dim3((EE + 255) / 256), dim3(256), 0, stream>>>(edst, cnt);
  k_scan1<<<dim3(NSCAN), dim3(256), 0, stream>>>(cnt, bsum);
  k_scan2<<<dim3(1), dim3(64), 0, stream>>>(bsum, off);
  k_scan3<<<dim3(NSCAN), dim3(256), 0, stream>>>(cnt, bsum, off);
  hipMemsetAsync(cnt, 0, NN * 4, stream);
  k_fill<<<dim3((EE + 255) / 256), dim3(256), 0, stream>>>(esrc, edst, off, cnt, csr);

  for (int l = 0; l < 4; l++) {
    if (l == 0)
      k_agg0<<<dim3((NN + 3) / 4), dim3(256), 0, stream>>>(x, off, csr, P, flag, T);
    else
      k_aggf<<<dim3((NN + 3) / 4), dim3(256), 0, stream>>>(X, off, csr, P, l, T);
    k_gemm_split<<<dim3((NN + 63) / 64), dim3(256), 0, stream>>>(T, W1hi + l * 16384, W1lo + l * 16384,
                                                                 P + O_B1 + l * 128, Pb);
    k_stats<<<dim3((NN + 511) / 512), dim3(256), 0, stream>>>(Pb, stats + (2 * l) * 256);
    k_bnapply<<<dim3((NN * 32 + 255) / 256), dim3(256), 0, stream>>>(Pb, stats + (2 * l) * 256,
                                                                     P + O_G1 + l * 128, P + O_BE1 + l * 128, T);
    k_gemm_split<<<dim3((NN + 63) / 64), dim3(256), 0, stream>>>(T, W2hi + l * 16384, W2lo + l * 16384,
                                                                 P + O_B2 + l * 128, Pb);
    k_stats<<<dim3((NN + 511) / 512), dim3(256), 0, stream>>>(Pb, stats + (2 * l + 1) * 256);
    k_bnapply<<<dim3((NN * 32 + 255) / 256), dim3(256), 0, stream>>>(Pb, stats + (2 * l + 1) * 256,
                                                                     P + O_G2 + l * 128, P + O_BE2 + l * 128, X);
    k_subpool<<<dim3((SS + 3) / 4), dim3(256), 0, stream>>>(X, n2s, sub, l);
  }
  k_graphpool<<<dim3((GG + 3) / 4), dim3(256), 0, stream>>>(sub, s2g, gph);
  k_head<<<dim3(GG), dim3(128), 0, stream>>>(gph, P, flag, (void*)d_out);
}

// Round 3
// 1446.150 us; speedup vs baseline: 1.5165x; 1.5165x over previous
//
#include <hip/hip_runtime.h>

typedef unsigned int u32;
typedef unsigned short u16;

#define NN 100000
#define EE 1600000
#define SS 10000
#define GG 256
#define NSCAN ((NN + 1023) / 1024)

// param block offsets (f32 elements)
#define O_W1   0
#define O_B1   65536
#define O_G1   66048
#define O_BE1  66560
#define O_W2   67072
#define O_B2   132608
#define O_G2   133120
#define O_BE2  133632
#define O_EPS  134144
#define O_L1W  134148
#define O_L1B  199684
#define O_L2W  199812
#define O_L2B  201092
#define NPAR   201102

typedef __bf16 bf16x8_t __attribute__((ext_vector_type(8)));
typedef float f32x4_t __attribute__((ext_vector_type(4)));
typedef u32 u32x4_t __attribute__((ext_vector_type(4)));

__device__ __forceinline__ float bf2f(u16 u) {
  union { u32 i; float f; } x; x.i = ((u32)u) << 16; return x.f;
}
__device__ __forceinline__ u16 f2bf(float f) {
  union { float f; u32 i; } x; x.f = f;
  u32 r = x.i + 0x7fffu + ((x.i >> 16) & 1u);
  return (u16)(r >> 16);
}
__device__ __forceinline__ int lbound(const int* __restrict__ a, int n, int key) {
  int lo = 0, hi = n;
  while (lo < hi) { int mid = (lo + hi) >> 1; if (a[mid] < key) lo = mid + 1; else hi = mid; }
  return lo;
}

// ---------------- dtype sniff: 1 = inputs are f32, 0 = bf16 ----------------
__global__ void k_sniff(const u16* __restrict__ x, int* __restrict__ flag) {
  __shared__ int cnt;
  if (threadIdx.x == 0) cnt = 0;
  __syncthreads();
  int weird = 0;
  for (int i = threadIdx.x; i < 8192; i += 256) {
    u16 v = x[i];
    int e = (v >> 7) & 0xff;
    if (e >= 0xC0) weird++;
  }
  atomicAdd(&cnt, weird);
  __syncthreads();
  if (threadIdx.x == 0) *flag = (cnt > 64) ? 1 : 0;
}

// ---------------- convert all params into f32 block P ----------------
__global__ __launch_bounds__(256) void k_cvt_params(
    const void* pW1, const void* pb1, const void* pg1, const void* pbe1,
    const void* pW2, const void* pb2, const void* pg2, const void* pbe2,
    const void* peps, const void* pl1w, const void* pl1b, const void* pl2w, const void* pl2b,
    const int* __restrict__ flagp, float* __restrict__ P) {
  int i = blockIdx.x * 256 + threadIdx.x;
  if (i >= NPAR) return;
  const void* src; int rel;
  if      (i < O_B1)  { src = pW1;  rel = i - O_W1; }
  else if (i < O_G1)  { src = pb1;  rel = i - O_B1; }
  else if (i < O_BE1) { src = pg1;  rel = i - O_G1; }
  else if (i < O_W2)  { src = pbe1; rel = i - O_BE1; }
  else if (i < O_B2)  { src = pW2;  rel = i - O_W2; }
  else if (i < O_G2)  { src = pb2;  rel = i - O_B2; }
  else if (i < O_BE2) { src = pg2;  rel = i - O_G2; }
  else if (i < O_EPS) { src = pbe2; rel = i - O_BE2; }
  else if (i < O_L1W) { src = peps; rel = i - O_EPS; }
  else if (i < O_L1B) { src = pl1w; rel = i - O_L1W; }
  else if (i < O_L2W) { src = pl1b; rel = i - O_L1B; }
  else if (i < O_L2B) { src = pl2w; rel = i - O_L2W; }
  else                { src = pl2b; rel = i - O_L2B; }
  float v = (*flagp) ? ((const float*)src)[rel] : bf2f(((const u16*)src)[rel]);
  P[i] = v;
}

// ---------------- W1/W2 -> bf16 ----------------
__global__ __launch_bounds__(256) void k_cvtW(const float* __restrict__ P,
                                              u16* __restrict__ W1b, u16* __restrict__ W2b) {
  int i = blockIdx.x * 256 + threadIdx.x;
  if (i >= 131072) return;
  if (i < 65536) W1b[i] = f2bf(P[O_W1 + i]);
  else           W2b[i - 65536] = f2bf(P[O_W2 + i - 65536]);
}

// ---------------- x -> Z0 bf16 ----------------
__global__ __launch_bounds__(256) void k_prep(const void* __restrict__ x, const int* __restrict__ flagp,
                                              u16* __restrict__ Z0) {
  int i = blockIdx.x * 256 + threadIdx.x;  // 8 elems per thread, 12.8M total
  if (i >= (NN * 128) / 8) return;
  if (*flagp) {
    const float4* xf = (const float4*)x;
    float4 a = xf[i * 2], b = xf[i * 2 + 1];
    u32x4_t o;
    o[0] = (u32)f2bf(a.x) | ((u32)f2bf(a.y) << 16);
    o[1] = (u32)f2bf(a.z) | ((u32)f2bf(a.w) << 16);
    o[2] = (u32)f2bf(b.x) | ((u32)f2bf(b.y) << 16);
    o[3] = (u32)f2bf(b.z) | ((u32)f2bf(b.w) << 16);
    *(u32x4_t*)(Z0 + i * 8) = o;
  } else {
    *(u32x4_t*)(Z0 + i * 8) = ((const u32x4_t*)x)[i];
  }
}

// ---------------- CSR build ----------------
__global__ __launch_bounds__(256) void k_hist(const int* __restrict__ dst, int* __restrict__ cnt) {
  int i = blockIdx.x * 256 + threadIdx.x;
  if (i < EE) atomicAdd(&cnt[dst[i]], 1);
}

__global__ __launch_bounds__(256) void k_scan1(const int* __restrict__ cnt, int* __restrict__ bsum) {
  __shared__ int sh[256];
  int base = blockIdx.x * 1024 + threadIdx.x * 4;
  int s = 0;
#pragma unroll
  for (int i = 0; i < 4; i++) { int idx = base + i; s += (idx < NN) ? cnt[idx] : 0; }
  sh[threadIdx.x] = s; __syncthreads();
  for (int o = 128; o > 0; o >>= 1) {
    if (threadIdx.x < o) sh[threadIdx.x] += sh[threadIdx.x + o];
    __syncthreads();
  }
  if (threadIdx.x == 0) bsum[blockIdx.x] = sh[0];
}

__global__ void k_scan2(int* __restrict__ bsum, int* __restrict__ off) {
  if (threadIdx.x == 0 && blockIdx.x == 0) {
    int run = 0;
    for (int i = 0; i < NSCAN; i++) { int v = bsum[i]; bsum[i] = run; run += v; }
    off[NN] = run;
  }
}

__global__ __launch_bounds__(256) void k_scan3(const int* __restrict__ cnt, const int* __restrict__ bsum,
                                               int* __restrict__ off) {
  __shared__ int sh[256];
  int base = blockIdx.x * 1024 + threadIdx.x * 4;
  int v[4]; int s = 0;
#pragma unroll
  for (int i = 0; i < 4; i++) { int idx = base + i; v[i] = (idx < NN) ? cnt[idx] : 0; s += v[i]; }
  sh[threadIdx.x] = s; __syncthreads();
  for (int o = 1; o < 256; o <<= 1) {
    int add = (threadIdx.x >= o) ? sh[threadIdx.x - o] : 0;
    __syncthreads();
    sh[threadIdx.x] += add;
    __syncthreads();
  }
  int run = sh[threadIdx.x] - s + bsum[blockIdx.x];
#pragma unroll
  for (int i = 0; i < 4; i++) { int idx = base + i; if (idx < NN) { off[idx] = run; run += v[i]; } }
}

__global__ __launch_bounds__(256) void k_fill(const int* __restrict__ src, const int* __restrict__ dst,
                                              const int* __restrict__ off, int* __restrict__ cur,
                                              int* __restrict__ csr) {
  int i = blockIdx.x * 256 + threadIdx.x;
  if (i >= EE) return;
  int d = dst[i];
  int p = off[d] + atomicAdd(&cur[d], 1);
  csr[p] = src[i];
}

// ---------------- fused: gather-agg -> LDS -> GEMM(W1) + stats1 ----------------
__global__ __launch_bounds__(256) void k_agg_gemm(
    const u16* __restrict__ Z, const int* __restrict__ off, const int* __restrict__ csr,
    const u16* __restrict__ Wb, const float* __restrict__ bias, const float* __restrict__ P,
    int layer, u16* __restrict__ H, float* __restrict__ st) {
  __shared__ __align__(16) u16 lds[4][16][136];
  __shared__ float sst[256];
  int wave = threadIdx.x >> 6, lane = threadIdx.x & 63;
  int r0 = blockIdx.x * 64 + wave * 16;
  sst[threadIdx.x] = 0.f;
  float ev = 1.0f + P[O_EPS + layer];
  const u32* zr = (const u32*)Z;
  for (int rr = 0; rr < 16; rr++) {
    int row = r0 + rr;
    float a0 = 0.f, a1 = 0.f;
    if (row < NN) {
      u32 d = zr[row * 64 + lane];
      a0 = ev * bf2f((u16)(d & 0xffffu));
      a1 = ev * bf2f((u16)(d >> 16));
      int i = off[row], e = off[row + 1];
      for (; i + 3 < e; i += 4) {
        int u0 = csr[i], u1 = csr[i + 1], u2 = csr[i + 2], u3 = csr[i + 3];
        u32 d0 = zr[u0 * 64 + lane];
        u32 d1 = zr[u1 * 64 + lane];
        u32 d2 = zr[u2 * 64 + lane];
        u32 d3 = zr[u3 * 64 + lane];
        a0 += bf2f((u16)(d0 & 0xffffu)) + bf2f((u16)(d1 & 0xffffu)) +
              bf2f((u16)(d2 & 0xffffu)) + bf2f((u16)(d3 & 0xffffu));
        a1 += bf2f((u16)(d0 >> 16)) + bf2f((u16)(d1 >> 16)) +
              bf2f((u16)(d2 >> 16)) + bf2f((u16)(d3 >> 16));
      }
      for (; i < e; i++) {
        u32 d0 = zr[csr[i] * 64 + lane];
        a0 += bf2f((u16)(d0 & 0xffffu));
        a1 += bf2f((u16)(d0 >> 16));
      }
    }
    ((u32*)&lds[wave][rr][0])[lane] = (u32)f2bf(a0) | ((u32)f2bf(a1) << 16);
  }
  __syncthreads();

  int nidx = lane & 15, q = lane >> 4;
  f32x4_t acc[8];
  f32x4_t z4 = {0.f, 0.f, 0.f, 0.f};
#pragma unroll
  for (int ot = 0; ot < 8; ot++) acc[ot] = z4;
#pragma unroll
  for (int ks = 0; ks < 4; ks++) {
    bf16x8_t af = __builtin_bit_cast(bf16x8_t, *(const u32x4_t*)&lds[wave][nidx][ks * 32 + q * 8]);
#pragma unroll
    for (int ot = 0; ot < 8; ot++) {
      bf16x8_t bfr = __builtin_bit_cast(bf16x8_t, *(const u32x4_t*)(Wb + (ot * 16 + nidx) * 128 + ks * 32 + q * 8));
      acc[ot] = __builtin_amdgcn_mfma_f32_16x16x32_bf16(af, bfr, acc[ot], 0, 0, 0);
    }
  }
#pragma unroll
  for (int ot = 0; ot < 8; ot++) {
    int col = ot * 16 + nidx;
    float bv = bias[col];
    float s = 0.f, sq = 0.f;
#pragma unroll
    for (int j = 0; j < 4; j++) {
      int row = r0 + q * 4 + j;
      if (row < NN) {
        float v = acc[ot][j] + bv;
        u16 h = f2bf(v);
        float vr = bf2f(h);
        H[row * 128 + col] = h;
        s += vr; sq += vr * vr;
      }
    }
    s  += __shfl_xor(s, 16, 64);  s  += __shfl_xor(s, 32, 64);
    sq += __shfl_xor(sq, 16, 64); sq += __shfl_xor(sq, 32, 64);
    if (q == 0) { atomicAdd(&sst[col], s); atomicAdd(&sst[128 + col], sq); }
  }
  __syncthreads();
  atomicAdd(&st[threadIdx.x], sst[threadIdx.x]);
}

// ---------------- fused: BN+ReLU(A) -> GEMM(W2) + stats2 ----------------
__global__ __launch_bounds__(256) void k_bn_gemm(
    const u16* __restrict__ Hin, const u16* __restrict__ Wb, const float* __restrict__ bias,
    const float* __restrict__ st_in, const float* __restrict__ gw, const float* __restrict__ bw,
    u16* __restrict__ Hout, float* __restrict__ st_out) {
  __shared__ float sc[256];
  __shared__ float sst[256];
  int t = threadIdx.x;
  sst[t] = 0.f;
  if (t < 128) {
    float mu = st_in[t] * (1.0f / NN);
    float var = st_in[128 + t] * (1.0f / NN) - mu * mu;
    var = fmaxf(var, 0.f);
    float r = rsqrtf(var + 1e-5f);
    float scl = gw[t] * r;
    sc[t] = scl;
    sc[128 + t] = bw[t] - mu * scl;
  }
  __syncthreads();
  int wave = t >> 6, lane = t & 63;
  int r0 = blockIdx.x * 64 + wave * 16;
  int nidx = lane & 15, q = lane >> 4;
  int arow = r0 + nidx;
  f32x4_t acc[8];
  f32x4_t z4 = {0.f, 0.f, 0.f, 0.f};
#pragma unroll
  for (int ot = 0; ot < 8; ot++) acc[ot] = z4;
  u32x4_t zero4 = {0, 0, 0, 0};
#pragma unroll
  for (int ks = 0; ks < 4; ks++) {
    int k0 = ks * 32 + q * 8;
    u32x4_t raw = (arow < NN) ? *(const u32x4_t*)(Hin + arow * 128 + k0) : zero4;
    u32x4_t ap;
#pragma unroll
    for (int w = 0; w < 4; w++) {
      int k = k0 + 2 * w;
      float v0 = fmaxf(bf2f((u16)(raw[w] & 0xffffu)) * sc[k] + sc[128 + k], 0.f);
      float v1 = fmaxf(bf2f((u16)(raw[w] >> 16)) * sc[k + 1] + sc[128 + k + 1], 0.f);
      ap[w] = (u32)f2bf(v0) | ((u32)f2bf(v1) << 16);
    }
    bf16x8_t af = __builtin_bit_cast(bf16x8_t, ap);
#pragma unroll
    for (int ot = 0; ot < 8; ot++) {
      bf16x8_t bfr = __builtin_bit_cast(bf16x8_t, *(const u32x4_t*)(Wb + (ot * 16 + nidx) * 128 + k0));
      acc[ot] = __builtin_amdgcn_mfma_f32_16x16x32_bf16(af, bfr, acc[ot], 0, 0, 0);
    }
  }
#pragma unroll
  for (int ot = 0; ot < 8; ot++) {
    int col = ot * 16 + nidx;
    float bv = bias[col];
    float s = 0.f, sq = 0.f;
#pragma unroll
    for (int j = 0; j < 4; j++) {
      int row = r0 + q * 4 + j;
      if (row < NN) {
        float v = acc[ot][j] + bv;
        u16 h = f2bf(v);
        float vr = bf2f(h);
        Hout[row * 128 + col] = h;
        s += vr; sq += vr * vr;
      }
    }
    s  += __shfl_xor(s, 16, 64);  s  += __shfl_xor(s, 32, 64);
    sq += __shfl_xor(sq, 16, 64); sq += __shfl_xor(sq, 32, 64);
    if (q == 0) { atomicAdd(&sst[col], s); atomicAdd(&sst[128 + col], sq); }
  }
  __syncthreads();
  atomicAdd(&st_out[t], sst[t]);
}

// ---------------- fused: BN2+ReLU -> Z_next bf16 + subgraph mean ----------------
__global__ __launch_bounds__(256) void k_bn_sub(
    const u16* __restrict__ Hin, const float* __restrict__ st_in, const float* __restrict__ gw,
    const float* __restrict__ bw, const int* __restrict__ n2s,
    u16* __restrict__ Znext, float* __restrict__ sub, int layer) {
  __shared__ float sc[256];
  int t = threadIdx.x;
  if (t < 128) {
    float mu = st_in[t] * (1.0f / NN);
    float var = st_in[128 + t] * (1.0f / NN) - mu * mu;
    var = fmaxf(var, 0.f);
    float r = rsqrtf(var + 1e-5f);
    float scl = gw[t] * r;
    sc[t] = scl;
    sc[128 + t] = bw[t] - mu * scl;
  }
  __syncthreads();
  int s = (blockIdx.x * 256 + t) >> 6;
  int lane = t & 63;
  if (s >= SS) return;
  int r0 = lbound(n2s, NN, s), r1 = lbound(n2s, NN, s + 1);
  float scl0 = sc[2 * lane], scl1 = sc[2 * lane + 1];
  float sh0 = sc[128 + 2 * lane], sh1 = sc[128 + 2 * lane + 1];
  const u32* hr = (const u32*)Hin;
  u32* zr = (u32*)Znext;
  float a0 = 0.f, a1 = 0.f;
  for (int r = r0; r < r1; r++) {
    u32 d = hr[r * 64 + lane];
    float v0 = fmaxf(bf2f((u16)(d & 0xffffu)) * scl0 + sh0, 0.f);
    float v1 = fmaxf(bf2f((u16)(d >> 16)) * scl1 + sh1, 0.f);
    zr[r * 64 + lane] = (u32)f2bf(v0) | ((u32)f2bf(v1) << 16);
    a0 += v0; a1 += v1;
  }
  int c = r1 - r0;
  float inv = 1.0f / (float)(c > 0 ? c : 1);
  float2 v; v.x = a0 * inv; v.y = a1 * inv;
  *(float2*)(sub + (size_t)s * 512 + layer * 128 + lane * 2) = v;
}

// ---------------- graph mean over subgraphs (sorted segments) ----------------
__global__ __launch_bounds__(256) void k_graphpool(const float* __restrict__ sub, const int* __restrict__ s2g,
                                                   float* __restrict__ gph) {
  int g = (blockIdx.x * 256 + threadIdx.x) >> 6;
  int lane = threadIdx.x & 63;
  if (g >= GG) return;
  int r0 = lbound(s2g, SS, g), r1 = lbound(s2g, SS, g + 1);
  float a[8] = {0.f, 0.f, 0.f, 0.f, 0.f, 0.f, 0.f, 0.f};
  for (int s = r0; s < r1; s++) {
    const float* row = sub + (size_t)s * 512 + lane * 8;
#pragma unroll
    for (int j = 0; j < 8; j++) a[j] += row[j];
  }
  int c = r1 - r0;
  float inv = 1.0f / (float)(c > 0 ? c : 1);
  float* orow = gph + (size_t)g * 512 + lane * 8;
#pragma unroll
  for (int j = 0; j < 8; j++) orow[j] = a[j] * inv;
}

// ---------------- head: lin1+relu, lin2, log_softmax ----------------
__global__ __launch_bounds__(128) void k_head(const float* __restrict__ gph, const float* __restrict__ P,
                                              const int* __restrict__ flagp, void* __restrict__ out) {
  __shared__ float gsh[512];
  __shared__ float hsh[128];
  __shared__ float lsh[12];
  int g = blockIdx.x, t = threadIdx.x;
  for (int i = t; i < 512; i += 128) gsh[i] = gph[(size_t)g * 512 + i];
  __syncthreads();
  float acc = P[O_L1B + t];
  const float4* wr = (const float4*)(P + O_L1W + t * 512);
  for (int kb = 0; kb < 128; kb++) {
    float4 w = wr[kb];
    int k = kb * 4;
    acc += gsh[k] * w.x + gsh[k + 1] * w.y + gsh[k + 2] * w.z + gsh[k + 3] * w.w;
  }
  hsh[t] = fmaxf(acc, 0.f);
  __syncthreads();
  if (t < 10) {
    float a = P[O_L2B + t];
    const float* w2r = P + O_L2W + t * 128;
    for (int k = 0; k < 128; k++) a += hsh[k] * w2r[k];
    lsh[t] = a;
  }
  __syncthreads();
  if (t == 0) {
    float m = -1e30f;
    for (int c = 0; c < 10; c++) m = fmaxf(m, lsh[c]);
    float se = 0.f;
    for (int c = 0; c < 10; c++) se += expf(lsh[c] - m);
    lsh[10] = m + logf(se);
  }
  __syncthreads();
  if (t < 10) {
    float v = lsh[t] - lsh[10];
    if (*flagp) ((float*)out)[g * 10 + t] = v;
    else        ((u16*)out)[g * 10 + t] = f2bf(v);
  }
}

extern "C" void kernel_launch(void* const* d_in, const int* in_sizes, int n_in,
                              void* d_out, int out_size, void* d_ws, size_t ws_size,
                              hipStream_t stream) {
  const void* x   = d_in[0];
  const int* ei   = (const int*)d_in[1];
  const int* n2s  = (const int*)d_in[2];
  const int* s2g  = (const int*)d_in[3];

  char* ws = (char*)d_ws;
  size_t o = 0;
  auto alloc = [&](size_t b) -> void* {
    void* p = ws + o;
    o += (b + 255) & ~(size_t)255;
    return p;
  };
  int* flag   = (int*)alloc(256);
  int* off    = (int*)alloc((NN + 1) * 4);
  int* cnt    = (int*)alloc(NN * 4);
  int* bsum   = (int*)alloc(NSCAN * 4);
  int* csr    = (int*)alloc((size_t)EE * 4);
  u16* zb0    = (u16*)alloc((size_t)NN * 128 * 2);
  u16* zb1    = (u16*)alloc((size_t)NN * 128 * 2);
  u16* H1     = (u16*)alloc((size_t)NN * 128 * 2);
  u16* H2     = (u16*)alloc((size_t)NN * 128 * 2);
  float* sub  = (float*)alloc((size_t)SS * 512 * 4);
  float* gph  = (float*)alloc((size_t)GG * 512 * 4);
  float* stats = (float*)alloc(8 * 256 * 4);
  float* P    = (float*)alloc((size_t)NPAR * 4);
  u16* W1b    = (u16*)alloc(65536 * 2);
  u16* W2b    = (u16*)alloc(65536 * 2);

  const int* esrc = ei;
  const int* edst = ei + EE;

  hipMemsetAsync(cnt, 0, NN * 4, stream);
  hipMemsetAsync(stats, 0, 8 * 256 * 4, stream);

  k_sniff<<<dim3(1), dim3(256), 0, stream>>>((const u16*)x, flag);
  k_cvt_params<<<dim3((NPAR + 255) / 256), dim3(256), 0, stream>>>(
      d_in[4], d_in[5], d_in[6], d_in[7], d_in[8], d_in[9], d_in[10], d_in[11],
      d_in[12], d_in[13], d_in[14], d_in[15], d_in[16], flag, P);
  k_cvtW<<<dim3(512), dim3(256), 0, stream>>>(P, W1b, W2b);
  k_prep<<<dim3((NN * 128 / 8 + 255) / 256), dim3(256), 0, stream>>>(x, flag, zb0);

  k_hist<<<dim3((EE + 255) / 256), dim3(256), 0, stream>>>(edst, cnt);
  k_scan1<<<dim3(NSCAN), dim3(256), 0, stream>>>(cnt, bsum);
  k_scan2<<<dim3(1), dim3(64), 0, stream>>>(bsum, off);
  k_scan3<<<dim3(NSCAN), dim3(256), 0, stream>>>(cnt, bsum, off);
  hipMemsetAsync(cnt, 0, NN * 4, stream);
  k_fill<<<dim3((EE + 255) / 256), dim3(256), 0, stream>>>(esrc, edst, off, cnt, csr);

  for (int l = 0; l < 4; l++) {
    const u16* Zin = (l == 0) ? zb0 : ((l & 1) ? zb1 : zb0);
    u16* Zout = (l & 1) ? zb0 : zb1;
    float* st1 = stats + (2 * l) * 256;
    float* st2 = stats + (2 * l + 1) * 256;
    k_agg_gemm<<<dim3((NN + 63) / 64), dim3(256), 0, stream>>>(
        Zin, off, csr, W1b + l * 16384, P + O_B1 + l * 128, P, l, H1, st1);
    k_bn_gemm<<<dim3((NN + 63) / 64), dim3(256), 0, stream>>>(
        H1, W2b + l * 16384, P + O_B2 + l * 128, st1, P + O_G1 + l * 128, P + O_BE1 + l * 128, H2, st2);
    k_bn_sub<<<dim3((SS + 3) / 4), dim3(256), 0, stream>>>(
        H2, st2, P + O_G2 + l * 128, P + O_BE2 + l * 128, n2s, Zout, sub, l);
  }
  k_graphpool<<<dim3((GG + 3) / 4), dim3(256), 0, stream>>>(sub, s2g, gph);
  k_head<<<dim3(GG), dim3(128), 0, stream>>>(gph, P, flag, (void*)d_out);
}

// Round 4
// 1273.996 us; speedup vs baseline: 1.7215x; 1.1351x over previous
//
#include <hip/hip_runtime.h>

typedef unsigned int u32;
typedef unsigned short u16;

#define NN 100000
#define EE 1600000
#define SS 10000
#define GG 256
#define NSCAN ((NN + 1023) / 1024)

// param block offsets (f32 elements)
#define O_W1   0
#define O_B1   65536
#define O_G1   66048
#define O_BE1  66560
#define O_W2   67072
#define O_B2   132608
#define O_G2   133120
#define O_BE2  133632
#define O_EPS  134144
#define O_L1W  134148
#define O_L1B  199684
#define O_L2W  199812
#define O_L2B  201092
#define NPAR   201102

typedef __bf16 bf16x8_t __attribute__((ext_vector_type(8)));
typedef float f32x4_t __attribute__((ext_vector_type(4)));
typedef u32 u32x4_t __attribute__((ext_vector_type(4)));

__device__ __forceinline__ float bf2f(u16 u) {
  union { u32 i; float f; } x; x.i = ((u32)u) << 16; return x.f;
}
__device__ __forceinline__ u16 f2bf(float f) {
  union { float f; u32 i; } x; x.f = f;
  u32 r = x.i + 0x7fffu + ((x.i >> 16) & 1u);
  return (u16)(r >> 16);
}
__device__ __forceinline__ int lbound(const int* __restrict__ a, int n, int key) {
  int lo = 0, hi = n;
  while (lo < hi) { int mid = (lo + hi) >> 1; if (a[mid] < key) lo = mid + 1; else hi = mid; }
  return lo;
}

// ---------------- dtype sniff: 1 = inputs are f32, 0 = bf16 ----------------
__global__ void k_sniff(const u16* __restrict__ x, int* __restrict__ flag) {
  __shared__ int cnt;
  if (threadIdx.x == 0) cnt = 0;
  __syncthreads();
  int weird = 0;
  for (int i = threadIdx.x; i < 8192; i += 256) {
    u16 v = x[i];
    int e = (v >> 7) & 0xff;
    if (e >= 0xC0) weird++;
  }
  atomicAdd(&cnt, weird);
  __syncthreads();
  if (threadIdx.x == 0) *flag = (cnt > 64) ? 1 : 0;
}

// ---------------- convert all params into f32 block P ----------------
__global__ __launch_bounds__(256) void k_cvt_params(
    const void* pW1, const void* pb1, const void* pg1, const void* pbe1,
    const void* pW2, const void* pb2, const void* pg2, const void* pbe2,
    const void* peps, const void* pl1w, const void* pl1b, const void* pl2w, const void* pl2b,
    const int* __restrict__ flagp, float* __restrict__ P) {
  int i = blockIdx.x * 256 + threadIdx.x;
  if (i >= NPAR) return;
  const void* src; int rel;
  if      (i < O_B1)  { src = pW1;  rel = i - O_W1; }
  else if (i < O_G1)  { src = pb1;  rel = i - O_B1; }
  else if (i < O_BE1) { src = pg1;  rel = i - O_G1; }
  else if (i < O_W2)  { src = pbe1; rel = i - O_BE1; }
  else if (i < O_B2)  { src = pW2;  rel = i - O_W2; }
  else if (i < O_G2)  { src = pb2;  rel = i - O_B2; }
  else if (i < O_BE2) { src = pg2;  rel = i - O_G2; }
  else if (i < O_EPS) { src = pbe2; rel = i - O_BE2; }
  else if (i < O_L1W) { src = peps; rel = i - O_EPS; }
  else if (i < O_L1B) { src = pl1w; rel = i - O_L1W; }
  else if (i < O_L2W) { src = pl1b; rel = i - O_L1B; }
  else if (i < O_L2B) { src = pl2w; rel = i - O_L2W; }
  else                { src = pl2b; rel = i - O_L2B; }
  float v = (*flagp) ? ((const float*)src)[rel] : bf2f(((const u16*)src)[rel]);
  P[i] = v;
}

// ---------------- W1/W2 -> bf16 ----------------
__global__ __launch_bounds__(256) void k_cvtW(const float* __restrict__ P,
                                              u16* __restrict__ W1b, u16* __restrict__ W2b) {
  int i = blockIdx.x * 256 + threadIdx.x;
  if (i >= 131072) return;
  if (i < 65536) W1b[i] = f2bf(P[O_W1 + i]);
  else           W2b[i - 65536] = f2bf(P[O_W2 + i - 65536]);
}

// ---------------- x -> Z0 bf16 ----------------
__global__ __launch_bounds__(256) void k_prep(const void* __restrict__ x, const int* __restrict__ flagp,
                                              u16* __restrict__ Z0) {
  int i = blockIdx.x * 256 + threadIdx.x;
  if (i >= (NN * 128) / 8) return;
  if (*flagp) {
    const float4* xf = (const float4*)x;
    float4 a = xf[i * 2], b = xf[i * 2 + 1];
    u32x4_t o;
    o[0] = (u32)f2bf(a.x) | ((u32)f2bf(a.y) << 16);
    o[1] = (u32)f2bf(a.z) | ((u32)f2bf(a.w) << 16);
    o[2] = (u32)f2bf(b.x) | ((u32)f2bf(b.y) << 16);
    o[3] = (u32)f2bf(b.z) | ((u32)f2bf(b.w) << 16);
    *(u32x4_t*)(Z0 + i * 8) = o;
  } else {
    *(u32x4_t*)(Z0 + i * 8) = ((const u32x4_t*)x)[i];
  }
}

// ---------------- CSR build ----------------
__global__ __launch_bounds__(256) void k_hist(const int* __restrict__ dst, int* __restrict__ cnt) {
  int i = blockIdx.x * 256 + threadIdx.x;
  if (i < EE) atomicAdd(&cnt[dst[i]], 1);
}

__global__ __launch_bounds__(256) void k_scan1(const int* __restrict__ cnt, int* __restrict__ bsum) {
  __shared__ int sh[256];
  int base = blockIdx.x * 1024 + threadIdx.x * 4;
  int s = 0;
#pragma unroll
  for (int i = 0; i < 4; i++) { int idx = base + i; s += (idx < NN) ? cnt[idx] : 0; }
  sh[threadIdx.x] = s; __syncthreads();
  for (int o = 128; o > 0; o >>= 1) {
    if (threadIdx.x < o) sh[threadIdx.x] += sh[threadIdx.x + o];
    __syncthreads();
  }
  if (threadIdx.x == 0) bsum[blockIdx.x] = sh[0];
}

__global__ void k_scan2(int* __restrict__ bsum, int* __restrict__ off) {
  if (threadIdx.x == 0 && blockIdx.x == 0) {
    int run = 0;
    for (int i = 0; i < NSCAN; i++) { int v = bsum[i]; bsum[i] = run; run += v; }
    off[NN] = run;
  }
}

__global__ __launch_bounds__(256) void k_scan3(const int* __restrict__ cnt, const int* __restrict__ bsum,
                                               int* __restrict__ off) {
  __shared__ int sh[256];
  int base = blockIdx.x * 1024 + threadIdx.x * 4;
  int v[4]; int s = 0;
#pragma unroll
  for (int i = 0; i < 4; i++) { int idx = base + i; v[i] = (idx < NN) ? cnt[idx] : 0; s += v[i]; }
  sh[threadIdx.x] = s; __syncthreads();
  for (int o = 1; o < 256; o <<= 1) {
    int add = (threadIdx.x >= o) ? sh[threadIdx.x - o] : 0;
    __syncthreads();
    sh[threadIdx.x] += add;
    __syncthreads();
  }
  int run = sh[threadIdx.x] - s + bsum[blockIdx.x];
#pragma unroll
  for (int i = 0; i < 4; i++) { int idx = base + i; if (idx < NN) { off[idx] = run; run += v[i]; } }
}

__global__ __launch_bounds__(256) void k_fill(const int* __restrict__ src, const int* __restrict__ dst,
                                              const int* __restrict__ off, int* __restrict__ cur,
                                              int* __restrict__ csr) {
  int i = blockIdx.x * 256 + threadIdx.x;
  if (i >= EE) return;
  int d = dst[i];
  int p = off[d] + atomicAdd(&cur[d], 1);
  csr[p] = src[i];
}

// ---------------- fused: gather-agg -> LDS -> GEMM(W1) + stats1 ----------------
// Single barrier; per-wave LDS tile + per-wave stats slices.
__global__ __launch_bounds__(256) void k_agg_gemm(
    const u16* __restrict__ Z, const int* __restrict__ off, const int* __restrict__ csr,
    const u16* __restrict__ Wb, const float* __restrict__ bias, const float* __restrict__ P,
    int layer, u16* __restrict__ H, float* __restrict__ st) {
  __shared__ __align__(16) u16 lds[4][16][136];
  __shared__ float sst[4][256];
  int wave = threadIdx.x >> 6, lane = threadIdx.x & 63;
  int r0 = blockIdx.x * 64 + wave * 16;
  float ev = 1.0f + P[O_EPS + layer];
  const u32* zr = (const u32*)Z;
  for (int rr = 0; rr < 16; rr++) {
    int row = r0 + rr;
    float a0 = 0.f, a1 = 0.f;
    if (row < NN) {
      u32 d = zr[row * 64 + lane];
      int i = off[row], e = off[row + 1];
      a0 = ev * bf2f((u16)(d & 0xffffu));
      a1 = ev * bf2f((u16)(d >> 16));
      for (; i + 7 < e; i += 8) {
        u32 dd[8];
#pragma unroll
        for (int j = 0; j < 8; j++) dd[j] = zr[csr[i + j] * 64 + lane];
#pragma unroll
        for (int j = 0; j < 8; j++) {
          a0 += bf2f((u16)(dd[j] & 0xffffu));
          a1 += bf2f((u16)(dd[j] >> 16));
        }
      }
      for (; i + 1 < e; i += 2) {
        u32 d0 = zr[csr[i] * 64 + lane];
        u32 d1 = zr[csr[i + 1] * 64 + lane];
        a0 += bf2f((u16)(d0 & 0xffffu)) + bf2f((u16)(d1 & 0xffffu));
        a1 += bf2f((u16)(d0 >> 16)) + bf2f((u16)(d1 >> 16));
      }
      if (i < e) {
        u32 d0 = zr[csr[i] * 64 + lane];
        a0 += bf2f((u16)(d0 & 0xffffu));
        a1 += bf2f((u16)(d0 >> 16));
      }
    }
    ((u32*)&lds[wave][rr][0])[lane] = (u32)f2bf(a0) | ((u32)f2bf(a1) << 16);
  }
  // NO barrier: each wave's LDS tile is private.
  int nidx = lane & 15, q = lane >> 4;
  f32x4_t acc[8];
  f32x4_t z4 = {0.f, 0.f, 0.f, 0.f};
#pragma unroll
  for (int ot = 0; ot < 8; ot++) acc[ot] = z4;
#pragma unroll
  for (int ks = 0; ks < 4; ks++) {
    bf16x8_t af = __builtin_bit_cast(bf16x8_t, *(const u32x4_t*)&lds[wave][nidx][ks * 32 + q * 8]);
#pragma unroll
    for (int ot = 0; ot < 8; ot++) {
      bf16x8_t bfr = __builtin_bit_cast(bf16x8_t, *(const u32x4_t*)(Wb + (ot * 16 + nidx) * 128 + ks * 32 + q * 8));
      acc[ot] = __builtin_amdgcn_mfma_f32_16x16x32_bf16(af, bfr, acc[ot], 0, 0, 0);
    }
  }
#pragma unroll
  for (int ot = 0; ot < 8; ot++) {
    int col = ot * 16 + nidx;
    float bv = bias[col];
    float s = 0.f, sq = 0.f;
#pragma unroll
    for (int j = 0; j < 4; j++) {
      int row = r0 + q * 4 + j;
      if (row < NN) {
        float v = acc[ot][j] + bv;
        u16 h = f2bf(v);
        float vr = bf2f(h);
        H[row * 128 + col] = h;
        s += vr; sq += vr * vr;
      }
    }
    s  += __shfl_xor(s, 16, 64);  s  += __shfl_xor(s, 32, 64);
    sq += __shfl_xor(sq, 16, 64); sq += __shfl_xor(sq, 32, 64);
    if (q == 0) { sst[wave][col] = s; sst[wave][128 + col] = sq; }
  }
  __syncthreads();
  int t = threadIdx.x;
  float tot = sst[0][t] + sst[1][t] + sst[2][t] + sst[3][t];
  atomicAdd(&st[t], tot);
}

// ---------------- fused: BN+ReLU(A) -> GEMM(W2) + stats2 ----------------
__global__ __launch_bounds__(256) void k_bn_gemm(
    const u16* __restrict__ Hin, const u16* __restrict__ Wb, const float* __restrict__ bias,
    const float* __restrict__ st_in, const float* __restrict__ gw, const float* __restrict__ bw,
    u16* __restrict__ Hout, float* __restrict__ st_out) {
  __shared__ float sc[256];
  __shared__ float sst[4][256];
  int t = threadIdx.x;
  if (t < 128) {
    float mu = st_in[t] * (1.0f / NN);
    float var = st_in[128 + t] * (1.0f / NN) - mu * mu;
    var = fmaxf(var, 0.f);
    float r = rsqrtf(var + 1e-5f);
    float scl = gw[t] * r;
    sc[t] = scl;
    sc[128 + t] = bw[t] - mu * scl;
  }
  __syncthreads();
  int wave = t >> 6, lane = t & 63;
  int r0 = blockIdx.x * 64 + wave * 16;
  int nidx = lane & 15, q = lane >> 4;
  int arow = r0 + nidx;
  u32x4_t zero4 = {0, 0, 0, 0};
  // prefetch entire A row segment (4 independent 16B loads)
  u32x4_t raw[4];
#pragma unroll
  for (int ks = 0; ks < 4; ks++)
    raw[ks] = (arow < NN) ? *(const u32x4_t*)(Hin + arow * 128 + ks * 32 + q * 8) : zero4;
  f32x4_t acc[8];
  f32x4_t z4 = {0.f, 0.f, 0.f, 0.f};
#pragma unroll
  for (int ot = 0; ot < 8; ot++) acc[ot] = z4;
#pragma unroll
  for (int ks = 0; ks < 4; ks++) {
    int k0 = ks * 32 + q * 8;
    u32x4_t ap;
#pragma unroll
    for (int w = 0; w < 4; w++) {
      int k = k0 + 2 * w;
      float v0 = fmaxf(bf2f((u16)(raw[ks][w] & 0xffffu)) * sc[k] + sc[128 + k], 0.f);
      float v1 = fmaxf(bf2f((u16)(raw[ks][w] >> 16)) * sc[k + 1] + sc[128 + k + 1], 0.f);
      ap[w] = (u32)f2bf(v0) | ((u32)f2bf(v1) << 16);
    }
    bf16x8_t af = __builtin_bit_cast(bf16x8_t, ap);
#pragma unroll
    for (int ot = 0; ot < 8; ot++) {
      bf16x8_t bfr = __builtin_bit_cast(bf16x8_t, *(const u32x4_t*)(Wb + (ot * 16 + nidx) * 128 + k0));
      acc[ot] = __builtin_amdgcn_mfma_f32_16x16x32_bf16(af, bfr, acc[ot], 0, 0, 0);
    }
  }
#pragma unroll
  for (int ot = 0; ot < 8; ot++) {
    int col = ot * 16 + nidx;
    float bv = bias[col];
    float s = 0.f, sq = 0.f;
#pragma unroll
    for (int j = 0; j < 4; j++) {
      int row = r0 + q * 4 + j;
      if (row < NN) {
        float v = acc[ot][j] + bv;
        u16 h = f2bf(v);
        float vr = bf2f(h);
        Hout[row * 128 + col] = h;
        s += vr; sq += vr * vr;
      }
    }
    s  += __shfl_xor(s, 16, 64);  s  += __shfl_xor(s, 32, 64);
    sq += __shfl_xor(sq, 16, 64); sq += __shfl_xor(sq, 32, 64);
    if (q == 0) { sst[wave][col] = s; sst[wave][128 + col] = sq; }
  }
  __syncthreads();
  float tot = sst[0][t] + sst[1][t] + sst[2][t] + sst[3][t];
  atomicAdd(&st_out[t], tot);
}

// ---------------- fused: BN2+ReLU -> Z_next bf16 + subgraph mean ----------------
__global__ __launch_bounds__(256) void k_bn_sub(
    const u16* __restrict__ Hin, const float* __restrict__ st_in, const float* __restrict__ gw,
    const float* __restrict__ bw, const int* __restrict__ n2s,
    u16* __restrict__ Znext, float* __restrict__ sub, int layer) {
  __shared__ float sc[256];
  int t = threadIdx.x;
  if (t < 128) {
    float mu = st_in[t] * (1.0f / NN);
    float var = st_in[128 + t] * (1.0f / NN) - mu * mu;
    var = fmaxf(var, 0.f);
    float r = rsqrtf(var + 1e-5f);
    float scl = gw[t] * r;
    sc[t] = scl;
    sc[128 + t] = bw[t] - mu * scl;
  }
  __syncthreads();
  int s = (blockIdx.x * 256 + t) >> 6;
  int lane = t & 63;
  if (s >= SS) return;
  int r0 = lbound(n2s, NN, s), r1 = lbound(n2s, NN, s + 1);
  float scl0 = sc[2 * lane], scl1 = sc[2 * lane + 1];
  float sh0 = sc[128 + 2 * lane], sh1 = sc[128 + 2 * lane + 1];
  const u32* hr = (const u32*)Hin;
  u32* zr = (u32*)Znext;
  float a0 = 0.f, a1 = 0.f;
  for (int r = r0; r < r1; r++) {
    u32 d = hr[r * 64 + lane];
    float v0 = fmaxf(bf2f((u16)(d & 0xffffu)) * scl0 + sh0, 0.f);
    float v1 = fmaxf(bf2f((u16)(d >> 16)) * scl1 + sh1, 0.f);
    zr[r * 64 + lane] = (u32)f2bf(v0) | ((u32)f2bf(v1) << 16);
    a0 += v0; a1 += v1;
  }
  int c = r1 - r0;
  float inv = 1.0f / (float)(c > 0 ? c : 1);
  float2 v; v.x = a0 * inv; v.y = a1 * inv;
  *(float2*)(sub + (size_t)s * 512 + layer * 128 + lane * 2) = v;
}

// ---------------- graph mean over subgraphs (sorted segments) ----------------
__global__ __launch_bounds__(256) void k_graphpool(const float* __restrict__ sub, const int* __restrict__ s2g,
                                                   float* __restrict__ gph) {
  int g = (blockIdx.x * 256 + threadIdx.x) >> 6;
  int lane = threadIdx.x & 63;
  if (g >= GG) return;
  int r0 = lbound(s2g, SS, g), r1 = lbound(s2g, SS, g + 1);
  float a[8] = {0.f, 0.f, 0.f, 0.f, 0.f, 0.f, 0.f, 0.f};
  for (int s = r0; s < r1; s++) {
    const float* row = sub + (size_t)s * 512 + lane * 8;
#pragma unroll
    for (int j = 0; j < 8; j++) a[j] += row[j];
  }
  int c = r1 - r0;
  float inv = 1.0f / (float)(c > 0 ? c : 1);
  float* orow = gph + (size_t)g * 512 + lane * 8;
#pragma unroll
  for (int j = 0; j < 8; j++) orow[j] = a[j] * inv;
}

// ---------------- head: lin1+relu, lin2, log_softmax ----------------
__global__ __launch_bounds__(128) void k_head(const float* __restrict__ gph, const float* __restrict__ P,
                                              const int* __restrict__ flagp, void* __restrict__ out) {
  __shared__ float gsh[512];
  __shared__ float hsh[128];
  __shared__ float lsh[12];
  int g = blockIdx.x, t = threadIdx.x;
  for (int i = t; i < 512; i += 128) gsh[i] = gph[(size_t)g * 512 + i];
  __syncthreads();
  float acc = P[O_L1B + t];
  const float4* wr = (const float4*)(P + O_L1W + t * 512);
  for (int kb = 0; kb < 128; kb++) {
    float4 w = wr[kb];
    int k = kb * 4;
    acc += gsh[k] * w.x + gsh[k + 1] * w.y + gsh[k + 2] * w.z + gsh[k + 3] * w.w;
  }
  hsh[t] = fmaxf(acc, 0.f);
  __syncthreads();
  if (t < 10) {
    float a = P[O_L2B + t];
    const float* w2r = P + O_L2W + t * 128;
    for (int k = 0; k < 128; k++) a += hsh[k] * w2r[k];
    lsh[t] = a;
  }
  __syncthreads();
  if (t == 0) {
    float m = -1e30f;
    for (int c = 0; c < 10; c++) m = fmaxf(m, lsh[c]);
    float se = 0.f;
    for (int c = 0; c < 10; c++) se += expf(lsh[c] - m);
    lsh[10] = m + logf(se);
  }
  __syncthreads();
  if (t < 10) {
    float v = lsh[t] - lsh[10];
    if (*flagp) ((float*)out)[g * 10 + t] = v;
    else        ((u16*)out)[g * 10 + t] = f2bf(v);
  }
}

extern "C" void kernel_launch(void* const* d_in, const int* in_sizes, int n_in,
                              void* d_out, int out_size, void* d_ws, size_t ws_size,
                              hipStream_t stream) {
  const void* x   = d_in[0];
  const int* ei   = (const int*)d_in[1];
  const int* n2s  = (const int*)d_in[2];
  const int* s2g  = (const int*)d_in[3];

  char* ws = (char*)d_ws;
  size_t o = 0;
  auto alloc = [&](size_t b) -> void* {
    void* p = ws + o;
    o += (b + 255) & ~(size_t)255;
    return p;
  };
  int* flag   = (int*)alloc(256);
  int* off    = (int*)alloc((NN + 1) * 4);
  int* cnt    = (int*)alloc(NN * 4);
  int* bsum   = (int*)alloc(NSCAN * 4);
  int* csr    = (int*)alloc((size_t)EE * 4);
  u16* zb0    = (u16*)alloc((size_t)NN * 128 * 2);
  u16* zb1    = (u16*)alloc((size_t)NN * 128 * 2);
  u16* H1     = (u16*)alloc((size_t)NN * 128 * 2);
  u16* H2     = (u16*)alloc((size_t)NN * 128 * 2);
  float* sub  = (float*)alloc((size_t)SS * 512 * 4);
  float* gph  = (float*)alloc((size_t)GG * 512 * 4);
  float* stats = (float*)alloc(8 * 256 * 4);
  float* P    = (float*)alloc((size_t)NPAR * 4);
  u16* W1b    = (u16*)alloc(65536 * 2);
  u16* W2b    = (u16*)alloc(65536 * 2);

  const int* esrc = ei;
  const int* edst = ei + EE;

  hipMemsetAsync(cnt, 0, NN * 4, stream);
  hipMemsetAsync(stats, 0, 8 * 256 * 4, stream);

  k_sniff<<<dim3(1), dim3(256), 0, stream>>>((const u16*)x, flag);
  k_cvt_params<<<dim3((NPAR + 255) / 256), dim3(256), 0, stream>>>(
      d_in[4], d_in[5], d_in[6], d_in[7], d_in[8], d_in[9], d_in[10], d_in[11],
      d_in[12], d_in[13], d_in[14], d_in[15], d_in[16], flag, P);
  k_cvtW<<<dim3(512), dim3(256), 0, stream>>>(P, W1b, W2b);
  k_prep<<<dim3((NN * 128 / 8 + 255) / 256), dim3(256), 0, stream>>>(x, flag, zb0);

  k_hist<<<dim3((EE + 255) / 256), dim3(256), 0, stream>>>(edst, cnt);
  k_scan1<<<dim3(NSCAN), dim3(256), 0, stream>>>(cnt, bsum);
  k_scan2<<<dim3(1), dim3(64), 0, stream>>>(bsum, off);
  k_scan3<<<dim3(NSCAN), dim3(256), 0, stream>>>(cnt, bsum, off);
  hipMemsetAsync(cnt, 0, NN * 4, stream);
  k_fill<<<dim3((EE + 255) / 256), dim3(256), 0, stream>>>(esrc, edst, off, cnt, csr);

  for (int l = 0; l < 4; l++) {
    const u16* Zin = (l == 0) ? zb0 : ((l & 1) ? zb1 : zb0);
    u16* Zout = (l & 1) ? zb0 : zb1;
    float* st1 = stats + (2 * l) * 256;
    float* st2 = stats + (2 * l + 1) * 256;
    k_agg_gemm<<<dim3((NN + 63) / 64), dim3(256), 0, stream>>>(
        Zin, off, csr, W1b + l * 16384, P + O_B1 + l * 128, P, l, H1, st1);
    k_bn_gemm<<<dim3((NN + 63) / 64), dim3(256), 0, stream>>>(
        H1, W2b + l * 16384, P + O_B2 + l * 128, st1, P + O_G1 + l * 128, P + O_BE1 + l * 128, H2, st2);
    k_bn_sub<<<dim3((SS + 3) / 4), dim3(256), 0, stream>>>(
        H2, st2, P + O_G2 + l * 128, P + O_BE2 + l * 128, n2s, Zout, sub, l);
  }
  k_graphpool<<<dim3((GG + 3) / 4), dim3(256), 0, stream>>>(sub, s2g, gph);
  k_head<<<dim3(GG), dim3(128), 0, stream>>>(gph, P, flag, (void*)d_out);
}

// Round 5
// 1218.107 us; speedup vs baseline: 1.8005x; 1.0459x over previous
//
#include <hip/hip_runtime.h>

typedef unsigned int u32;
typedef unsigned short u16;

#define NN 100000
#define EE 1600000
#define SS 10000
#define GG 256
#define NSCAN ((NN + 1023) / 1024)

// param block offsets (f32 elements)
#define O_W1   0
#define O_B1   65536
#define O_G1   66048
#define O_BE1  66560
#define O_W2   67072
#define O_B2   132608
#define O_G2   133120
#define O_BE2  133632
#define O_EPS  134144
#define O_L1W  134148
#define O_L1B  199684
#define O_L2W  199812
#define O_L2B  201092
#define NPAR   201102

typedef __bf16 bf16x8_t __attribute__((ext_vector_type(8)));
typedef float f32x4_t __attribute__((ext_vector_type(4)));
typedef u32 u32x4_t __attribute__((ext_vector_type(4)));

__device__ __forceinline__ float bf2f(u16 u) {
  union { u32 i; float f; } x; x.i = ((u32)u) << 16; return x.f;
}
__device__ __forceinline__ u16 f2bf(float f) {
  union { float f; u32 i; } x; x.f = f;
  u32 r = x.i + 0x7fffu + ((x.i >> 16) & 1u);
  return (u16)(r >> 16);
}
__device__ __forceinline__ int lbound(const int* __restrict__ a, int n, int key) {
  int lo = 0, hi = n;
  while (lo < hi) { int mid = (lo + hi) >> 1; if (a[mid] < key) lo = mid + 1; else hi = mid; }
  return lo;
}

// ---------------- dtype sniff: 1 = inputs are f32, 0 = bf16 ----------------
__global__ void k_sniff(const u16* __restrict__ x, int* __restrict__ flag) {
  __shared__ int cnt;
  if (threadIdx.x == 0) cnt = 0;
  __syncthreads();
  int weird = 0;
  for (int i = threadIdx.x; i < 8192; i += 256) {
    u16 v = x[i];
    int e = (v >> 7) & 0xff;
    if (e >= 0xC0) weird++;
  }
  atomicAdd(&cnt, weird);
  __syncthreads();
  if (threadIdx.x == 0) *flag = (cnt > 64) ? 1 : 0;
}

// ---------------- convert all params into f32 block P ----------------
__global__ __launch_bounds__(256) void k_cvt_params(
    const void* pW1, const void* pb1, const void* pg1, const void* pbe1,
    const void* pW2, const void* pb2, const void* pg2, const void* pbe2,
    const void* peps, const void* pl1w, const void* pl1b, const void* pl2w, const void* pl2b,
    const int* __restrict__ flagp, float* __restrict__ P) {
  int i = blockIdx.x * 256 + threadIdx.x;
  if (i >= NPAR) return;
  const void* src; int rel;
  if      (i < O_B1)  { src = pW1;  rel = i - O_W1; }
  else if (i < O_G1)  { src = pb1;  rel = i - O_B1; }
  else if (i < O_BE1) { src = pg1;  rel = i - O_G1; }
  else if (i < O_W2)  { src = pbe1; rel = i - O_BE1; }
  else if (i < O_B2)  { src = pW2;  rel = i - O_W2; }
  else if (i < O_G2)  { src = pb2;  rel = i - O_B2; }
  else if (i < O_BE2) { src = pg2;  rel = i - O_G2; }
  else if (i < O_EPS) { src = pbe2; rel = i - O_BE2; }
  else if (i < O_L1W) { src = peps; rel = i - O_EPS; }
  else if (i < O_L1B) { src = pl1w; rel = i - O_L1W; }
  else if (i < O_L2W) { src = pl1b; rel = i - O_L1B; }
  else if (i < O_L2B) { src = pl2w; rel = i - O_L2W; }
  else                { src = pl2b; rel = i - O_L2B; }
  float v = (*flagp) ? ((const float*)src)[rel] : bf2f(((const u16*)src)[rel]);
  P[i] = v;
}

// ---------------- W1/W2 -> bf16 ----------------
__global__ __launch_bounds__(256) void k_cvtW(const float* __restrict__ P,
                                              u16* __restrict__ W1b, u16* __restrict__ W2b) {
  int i = blockIdx.x * 256 + threadIdx.x;
  if (i >= 131072) return;
  if (i < 65536) W1b[i] = f2bf(P[O_W1 + i]);
  else           W2b[i - 65536] = f2bf(P[O_W2 + i - 65536]);
}

// ---------------- x -> Z0 bf16 ----------------
__global__ __launch_bounds__(256) void k_prep(const void* __restrict__ x, const int* __restrict__ flagp,
                                              u16* __restrict__ Z0) {
  int i = blockIdx.x * 256 + threadIdx.x;
  if (i >= (NN * 128) / 8) return;
  if (*flagp) {
    const float4* xf = (const float4*)x;
    float4 a = xf[i * 2], b = xf[i * 2 + 1];
    u32x4_t o;
    o[0] = (u32)f2bf(a.x) | ((u32)f2bf(a.y) << 16);
    o[1] = (u32)f2bf(a.z) | ((u32)f2bf(a.w) << 16);
    o[2] = (u32)f2bf(b.x) | ((u32)f2bf(b.y) << 16);
    o[3] = (u32)f2bf(b.z) | ((u32)f2bf(b.w) << 16);
    *(u32x4_t*)(Z0 + i * 8) = o;
  } else {
    *(u32x4_t*)(Z0 + i * 8) = ((const u32x4_t*)x)[i];
  }
}

// ---------------- CSR build ----------------
__global__ __launch_bounds__(256) void k_hist(const int* __restrict__ dst, int* __restrict__ cnt) {
  int i = blockIdx.x * 256 + threadIdx.x;
  if (i < EE) atomicAdd(&cnt[dst[i]], 1);
}

__global__ __launch_bounds__(256) void k_scan1(const int* __restrict__ cnt, int* __restrict__ bsum) {
  __shared__ int sh[256];
  int base = blockIdx.x * 1024 + threadIdx.x * 4;
  int s = 0;
#pragma unroll
  for (int i = 0; i < 4; i++) { int idx = base + i; s += (idx < NN) ? cnt[idx] : 0; }
  sh[threadIdx.x] = s; __syncthreads();
  for (int o = 128; o > 0; o >>= 1) {
    if (threadIdx.x < o) sh[threadIdx.x] += sh[threadIdx.x + o];
    __syncthreads();
  }
  if (threadIdx.x == 0) bsum[blockIdx.x] = sh[0];
}

__global__ void k_scan2(int* __restrict__ bsum, int* __restrict__ off) {
  if (threadIdx.x == 0 && blockIdx.x == 0) {
    int run = 0;
    for (int i = 0; i < NSCAN; i++) { int v = bsum[i]; bsum[i] = run; run += v; }
    off[NN] = run;
  }
}

__global__ __launch_bounds__(256) void k_scan3(const int* __restrict__ cnt, const int* __restrict__ bsum,
                                               int* __restrict__ off) {
  __shared__ int sh[256];
  int base = blockIdx.x * 1024 + threadIdx.x * 4;
  int v[4]; int s = 0;
#pragma unroll
  for (int i = 0; i < 4; i++) { int idx = base + i; v[i] = (idx < NN) ? cnt[idx] : 0; s += v[i]; }
  sh[threadIdx.x] = s; __syncthreads();
  for (int o = 1; o < 256; o <<= 1) {
    int add = (threadIdx.x >= o) ? sh[threadIdx.x - o] : 0;
    __syncthreads();
    sh[threadIdx.x] += add;
    __syncthreads();
  }
  int run = sh[threadIdx.x] - s + bsum[blockIdx.x];
#pragma unroll
  for (int i = 0; i < 4; i++) { int idx = base + i; if (idx < NN) { off[idx] = run; run += v[i]; } }
}

__global__ __launch_bounds__(256) void k_fill(const int* __restrict__ src, const int* __restrict__ dst,
                                              const int* __restrict__ off, int* __restrict__ cur,
                                              int* __restrict__ csr) {
  int i = blockIdx.x * 256 + threadIdx.x;
  if (i >= EE) return;
  int d = dst[i];
  int p = off[d] + atomicAdd(&cur[d], 1);
  csr[p] = src[i];
}

// ---------------- fused: gather-agg -> LDS -> GEMM(W1) + stats1 ----------------
// Wave-private LDS-staged neighbor indices: only gathers carry global latency.
__global__ __launch_bounds__(256) void k_agg_gemm(
    const u16* __restrict__ Z, const int* __restrict__ off, const int* __restrict__ csr,
    const u16* __restrict__ Wb, const float* __restrict__ bias, const float* __restrict__ P,
    int layer, u16* __restrict__ H, float* __restrict__ st) {
  __shared__ __align__(16) u16 lds[4][16][136];
  __shared__ __align__(16) int shidx[4][512];   // idx staging; aliased as stats slice later
  int wave = threadIdx.x >> 6, lane = threadIdx.x & 63;
  int r0 = blockIdx.x * 64 + wave * 16;
  float ev = 1.0f + P[O_EPS + layer];
  const u32* zr = (const u32*)Z;

  // prefetch off[r0 .. r0+16] (clamped) via lanes 0..16
  int offv = 0;
  if (lane <= 16) {
    int rr = r0 + lane; if (rr > NN) rr = NN; if (rr < 0) rr = 0;
    offv = off[rr];
  }
  int ebase = __shfl(offv, 0, 64);
  int eend  = __shfl(offv, 16, 64);
  int tn = eend - ebase;
  int nst = tn < 512 ? tn : 512;
  // stage neighbor indices (coalesced, wave-private region -> no barrier)
  for (int i = lane; i < nst; i += 64) shidx[wave][i] = csr[ebase + i];

  for (int rr = 0; rr < 16; rr++) {
    int row = r0 + rr;
    float a0 = 0.f, a1 = 0.f;
    if (row < NN) {
      int s = __shfl(offv, rr, 64), e = __shfl(offv, rr + 1, 64);
      int n = e - s, b = s - ebase;
      u32 d = zr[row * 64 + lane];
      a0 = ev * bf2f((u16)(d & 0xffffu));
      a1 = ev * bf2f((u16)(d >> 16));
      const int* ip = (b + n <= 512) ? &shidx[wave][b] : &csr[s];
      int i = 0;
      for (; i + 7 < n; i += 8) {
        u32 dd[8];
#pragma unroll
        for (int j = 0; j < 8; j++) dd[j] = zr[ip[i + j] * 64 + lane];
#pragma unroll
        for (int j = 0; j < 8; j++) {
          a0 += bf2f((u16)(dd[j] & 0xffffu));
          a1 += bf2f((u16)(dd[j] >> 16));
        }
      }
      for (; i + 1 < n; i += 2) {
        u32 d0 = zr[ip[i] * 64 + lane];
        u32 d1 = zr[ip[i + 1] * 64 + lane];
        a0 += bf2f((u16)(d0 & 0xffffu)) + bf2f((u16)(d1 & 0xffffu));
        a1 += bf2f((u16)(d0 >> 16)) + bf2f((u16)(d1 >> 16));
      }
      if (i < n) {
        u32 d0 = zr[ip[i] * 64 + lane];
        a0 += bf2f((u16)(d0 & 0xffffu));
        a1 += bf2f((u16)(d0 >> 16));
      }
    }
    ((u32*)&lds[wave][rr][0])[lane] = (u32)f2bf(a0) | ((u32)f2bf(a1) << 16);
  }

  // MFMA over the wave-private tile (no barrier needed)
  int nidx = lane & 15, q = lane >> 4;
  f32x4_t acc[8];
  f32x4_t z4 = {0.f, 0.f, 0.f, 0.f};
#pragma unroll
  for (int ot = 0; ot < 8; ot++) acc[ot] = z4;
#pragma unroll
  for (int ks = 0; ks < 4; ks++) {
    bf16x8_t af = __builtin_bit_cast(bf16x8_t, *(const u32x4_t*)&lds[wave][nidx][ks * 32 + q * 8]);
#pragma unroll
    for (int ot = 0; ot < 8; ot++) {
      bf16x8_t bfr = __builtin_bit_cast(bf16x8_t, *(const u32x4_t*)(Wb + (ot * 16 + nidx) * 128 + ks * 32 + q * 8));
      acc[ot] = __builtin_amdgcn_mfma_f32_16x16x32_bf16(af, bfr, acc[ot], 0, 0, 0);
    }
  }
  float* sstw = (float*)&shidx[wave][0];  // done with this wave's idx region
#pragma unroll
  for (int ot = 0; ot < 8; ot++) {
    int col = ot * 16 + nidx;
    float bv = bias[col];
    float s = 0.f, sq = 0.f;
#pragma unroll
    for (int j = 0; j < 4; j++) {
      int row = r0 + q * 4 + j;
      if (row < NN) {
        float v = acc[ot][j] + bv;
        u16 h = f2bf(v);
        float vr = bf2f(h);
        H[row * 128 + col] = h;
        s += vr; sq += vr * vr;
      }
    }
    s  += __shfl_xor(s, 16, 64);  s  += __shfl_xor(s, 32, 64);
    sq += __shfl_xor(sq, 16, 64); sq += __shfl_xor(sq, 32, 64);
    if (q == 0) { sstw[col] = s; sstw[128 + col] = sq; }
  }
  __syncthreads();
  int t = threadIdx.x;
  float tot = ((float*)&shidx[0][0])[t] + ((float*)&shidx[1][0])[t] +
              ((float*)&shidx[2][0])[t] + ((float*)&shidx[3][0])[t];
  atomicAdd(&st[t], tot);
}

// ---------------- fused: BN+ReLU(A) -> GEMM(W2) + stats2 ----------------
__global__ __launch_bounds__(256) void k_bn_gemm(
    const u16* __restrict__ Hin, const u16* __restrict__ Wb, const float* __restrict__ bias,
    const float* __restrict__ st_in, const float* __restrict__ gw, const float* __restrict__ bw,
    u16* __restrict__ Hout, float* __restrict__ st_out) {
  __shared__ float sc[256];
  __shared__ float sst[4][256];
  int t = threadIdx.x;
  if (t < 128) {
    float mu = st_in[t] * (1.0f / NN);
    float var = st_in[128 + t] * (1.0f / NN) - mu * mu;
    var = fmaxf(var, 0.f);
    float r = rsqrtf(var + 1e-5f);
    float scl = gw[t] * r;
    sc[t] = scl;
    sc[128 + t] = bw[t] - mu * scl;
  }
  __syncthreads();
  int wave = t >> 6, lane = t & 63;
  int r0 = blockIdx.x * 64 + wave * 16;
  int nidx = lane & 15, q = lane >> 4;
  int arow = r0 + nidx;
  u32x4_t zero4 = {0, 0, 0, 0};
  u32x4_t raw[4];
#pragma unroll
  for (int ks = 0; ks < 4; ks++)
    raw[ks] = (arow < NN) ? *(const u32x4_t*)(Hin + arow * 128 + ks * 32 + q * 8) : zero4;
  f32x4_t acc[8];
  f32x4_t z4 = {0.f, 0.f, 0.f, 0.f};
#pragma unroll
  for (int ot = 0; ot < 8; ot++) acc[ot] = z4;
#pragma unroll
  for (int ks = 0; ks < 4; ks++) {
    int k0 = ks * 32 + q * 8;
    u32x4_t ap;
#pragma unroll
    for (int w = 0; w < 4; w++) {
      int k = k0 + 2 * w;
      float v0 = fmaxf(bf2f((u16)(raw[ks][w] & 0xffffu)) * sc[k] + sc[128 + k], 0.f);
      float v1 = fmaxf(bf2f((u16)(raw[ks][w] >> 16)) * sc[k + 1] + sc[128 + k + 1], 0.f);
      ap[w] = (u32)f2bf(v0) | ((u32)f2bf(v1) << 16);
    }
    bf16x8_t af = __builtin_bit_cast(bf16x8_t, ap);
#pragma unroll
    for (int ot = 0; ot < 8; ot++) {
      bf16x8_t bfr = __builtin_bit_cast(bf16x8_t, *(const u32x4_t*)(Wb + (ot * 16 + nidx) * 128 + k0));
      acc[ot] = __builtin_amdgcn_mfma_f32_16x16x32_bf16(af, bfr, acc[ot], 0, 0, 0);
    }
  }
#pragma unroll
  for (int ot = 0; ot < 8; ot++) {
    int col = ot * 16 + nidx;
    float bv = bias[col];
    float s = 0.f, sq = 0.f;
#pragma unroll
    for (int j = 0; j < 4; j++) {
      int row = r0 + q * 4 + j;
      if (row < NN) {
        float v = acc[ot][j] + bv;
        u16 h = f2bf(v);
        float vr = bf2f(h);
        Hout[row * 128 + col] = h;
        s += vr; sq += vr * vr;
      }
    }
    s  += __shfl_xor(s, 16, 64);  s  += __shfl_xor(s, 32, 64);
    sq += __shfl_xor(sq, 16, 64); sq += __shfl_xor(sq, 32, 64);
    if (q == 0) { sst[wave][col] = s; sst[wave][128 + col] = sq; }
  }
  __syncthreads();
  float tot = sst[0][t] + sst[1][t] + sst[2][t] + sst[3][t];
  atomicAdd(&st_out[t], tot);
}

// ---------------- fused: BN2+ReLU -> Z_next bf16 + subgraph mean ----------------
__global__ __launch_bounds__(256) void k_bn_sub(
    const u16* __restrict__ Hin, const float* __restrict__ st_in, const float* __restrict__ gw,
    const float* __restrict__ bw, const int* __restrict__ n2s,
    u16* __restrict__ Znext, float* __restrict__ sub, int layer) {
  __shared__ float sc[256];
  int t = threadIdx.x;
  if (t < 128) {
    float mu = st_in[t] * (1.0f / NN);
    float var = st_in[128 + t] * (1.0f / NN) - mu * mu;
    var = fmaxf(var, 0.f);
    float r = rsqrtf(var + 1e-5f);
    float scl = gw[t] * r;
    sc[t] = scl;
    sc[128 + t] = bw[t] - mu * scl;
  }
  __syncthreads();
  int s = (blockIdx.x * 256 + t) >> 6;
  int lane = t & 63;
  if (s >= SS) return;
  int r0 = lbound(n2s, NN, s), r1 = lbound(n2s, NN, s + 1);
  float scl0 = sc[2 * lane], scl1 = sc[2 * lane + 1];
  float sh0 = sc[128 + 2 * lane], sh1 = sc[128 + 2 * lane + 1];
  const u32* hr = (const u32*)Hin;
  u32* zr = (u32*)Znext;
  float a0 = 0.f, a1 = 0.f;
  for (int r = r0; r < r1; r++) {
    u32 d = hr[r * 64 + lane];
    float v0 = fmaxf(bf2f((u16)(d & 0xffffu)) * scl0 + sh0, 0.f);
    float v1 = fmaxf(bf2f((u16)(d >> 16)) * scl1 + sh1, 0.f);
    zr[r * 64 + lane] = (u32)f2bf(v0) | ((u32)f2bf(v1) << 16);
    a0 += v0; a1 += v1;
  }
  int c = r1 - r0;
  float inv = 1.0f / (float)(c > 0 ? c : 1);
  float2 v; v.x = a0 * inv; v.y = a1 * inv;
  *(float2*)(sub + (size_t)s * 512 + layer * 128 + lane * 2) = v;
}

// ---------------- graph mean over subgraphs (sorted segments) ----------------
__global__ __launch_bounds__(256) void k_graphpool(const float* __restrict__ sub, const int* __restrict__ s2g,
                                                   float* __restrict__ gph) {
  int g = (blockIdx.x * 256 + threadIdx.x) >> 6;
  int lane = threadIdx.x & 63;
  if (g >= GG) return;
  int r0 = lbound(s2g, SS, g), r1 = lbound(s2g, SS, g + 1);
  float a[8] = {0.f, 0.f, 0.f, 0.f, 0.f, 0.f, 0.f, 0.f};
  for (int s = r0; s < r1; s++) {
    const float* row = sub + (size_t)s * 512 + lane * 8;
#pragma unroll
    for (int j = 0; j < 8; j++) a[j] += row[j];
  }
  int c = r1 - r0;
  float inv = 1.0f / (float)(c > 0 ? c : 1);
  float* orow = gph + (size_t)g * 512 + lane * 8;
#pragma unroll
  for (int j = 0; j < 8; j++) orow[j] = a[j] * inv;
}

// ---------------- head: lin1+relu, lin2, log_softmax ----------------
__global__ __launch_bounds__(128) void k_head(const float* __restrict__ gph, const float* __restrict__ P,
                                              const int* __restrict__ flagp, void* __restrict__ out) {
  __shared__ float gsh[512];
  __shared__ float hsh[128];
  __shared__ float lsh[12];
  int g = blockIdx.x, t = threadIdx.x;
  for (int i = t; i < 512; i += 128) gsh[i] = gph[(size_t)g * 512 + i];
  __syncthreads();
  float acc = P[O_L1B + t];
  const float4* wr = (const float4*)(P + O_L1W + t * 512);
  for (int kb = 0; kb < 128; kb++) {
    float4 w = wr[kb];
    int k = kb * 4;
    acc += gsh[k] * w.x + gsh[k + 1] * w.y + gsh[k + 2] * w.z + gsh[k + 3] * w.w;
  }
  hsh[t] = fmaxf(acc, 0.f);
  __syncthreads();
  if (t < 10) {
    float a = P[O_L2B + t];
    const float* w2r = P + O_L2W + t * 128;
    for (int k = 0; k < 128; k++) a += hsh[k] * w2r[k];
    lsh[t] = a;
  }
  __syncthreads();
  if (t == 0) {
    float m = -1e30f;
    for (int c = 0; c < 10; c++) m = fmaxf(m, lsh[c]);
    float se = 0.f;
    for (int c = 0; c < 10; c++) se += expf(lsh[c] - m);
    lsh[10] = m + logf(se);
  }
  __syncthreads();
  if (t < 10) {
    float v = lsh[t] - lsh[10];
    if (*flagp) ((float*)out)[g * 10 + t] = v;
    else        ((u16*)out)[g * 10 + t] = f2bf(v);
  }
}

extern "C" void kernel_launch(void* const* d_in, const int* in_sizes, int n_in,
                              void* d_out, int out_size, void* d_ws, size_t ws_size,
                              hipStream_t stream) {
  const void* x   = d_in[0];
  const int* ei   = (const int*)d_in[1];
  const int* n2s  = (const int*)d_in[2];
  const int* s2g  = (const int*)d_in[3];

  char* ws = (char*)d_ws;
  size_t o = 0;
  auto alloc = [&](size_t b) -> void* {
    void* p = ws + o;
    o += (b + 255) & ~(size_t)255;
    return p;
  };
  int* flag   = (int*)alloc(256);
  int* off    = (int*)alloc((NN + 1) * 4);
  int* cnt    = (int*)alloc(NN * 4);
  int* bsum   = (int*)alloc(NSCAN * 4);
  int* csr    = (int*)alloc((size_t)EE * 4);
  u16* zb0    = (u16*)alloc((size_t)NN * 128 * 2);
  u16* zb1    = (u16*)alloc((size_t)NN * 128 * 2);
  u16* H1     = (u16*)alloc((size_t)NN * 128 * 2);
  u16* H2     = (u16*)alloc((size_t)NN * 128 * 2);
  float* sub  = (float*)alloc((size_t)SS * 512 * 4);
  float* gph  = (float*)alloc((size_t)GG * 512 * 4);
  float* stats = (float*)alloc(8 * 256 * 4);
  float* P    = (float*)alloc((size_t)NPAR * 4);
  u16* W1b    = (u16*)alloc(65536 * 2);
  u16* W2b    = (u16*)alloc(65536 * 2);

  const int* esrc = ei;
  const int* edst = ei + EE;

  hipMemsetAsync(cnt, 0, NN * 4, stream);
  hipMemsetAsync(stats, 0, 8 * 256 * 4, stream);

  k_sniff<<<dim3(1), dim3(256), 0, stream>>>((const u16*)x, flag);
  k_cvt_params<<<dim3((NPAR + 255) / 256), dim3(256), 0, stream>>>(
      d_in[4], d_in[5], d_in[6], d_in[7], d_in[8], d_in[9], d_in[10], d_in[11],
      d_in[12], d_in[13], d_in[14], d_in[15], d_in[16], flag, P);
  k_cvtW<<<dim3(512), dim3(256), 0, stream>>>(P, W1b, W2b);
  k_prep<<<dim3((NN * 128 / 8 + 255) / 256), dim3(256), 0, stream>>>(x, flag, zb0);

  k_hist<<<dim3((EE + 255) / 256), dim3(256), 0, stream>>>(edst, cnt);
  k_scan1<<<dim3(NSCAN), dim3(256), 0, stream>>>(cnt, bsum);
  k_scan2<<<dim3(1), dim3(64), 0, stream>>>(bsum, off);
  k_scan3<<<dim3(NSCAN), dim3(256), 0, stream>>>(cnt, bsum, off);
  hipMemsetAsync(cnt, 0, NN * 4, stream);
  k_fill<<<dim3((EE + 255) / 256), dim3(256), 0, stream>>>(esrc, edst, off, cnt, csr);

  for (int l = 0; l < 4; l++) {
    const u16* Zin = (l == 0) ? zb0 : ((l & 1) ? zb1 : zb0);
    u16* Zout = (l & 1) ? zb0 : zb1;
    float* st1 = stats + (2 * l) * 256;
    float* st2 = stats + (2 * l + 1) * 256;
    k_agg_gemm<<<dim3((NN + 63) / 64), dim3(256), 0, stream>>>(
        Zin, off, csr, W1b + l * 16384, P + O_B1 + l * 128, P, l, H1, st1);
    k_bn_gemm<<<dim3((NN + 63) / 64), dim3(256), 0, stream>>>(
        H1, W2b + l * 16384, P + O_B2 + l * 128, st1, P + O_G1 + l * 128, P + O_BE1 + l * 128, H2, st2);
    k_bn_sub<<<dim3((SS + 3) / 4), dim3(256), 0, stream>>>(
        H2, st2, P + O_G2 + l * 128, P + O_BE2 + l * 128, n2s, Zout, sub, l);
  }
  k_graphpool<<<dim3((GG + 3) / 4), dim3(256), 0, stream>>>(sub, s2g, gph);
  k_head<<<dim3(GG), dim3(128), 0, stream>>>(gph, P, flag, (void*)d_out);
}